// Round 1
// baseline (156.701 us; speedup 1.0000x reference)
//
#include <hip/hip_runtime.h>

#define BATCH 8
#define CCH 8
#define HW 262144       // 512*512
#define SEGS 16         // segments 1..16 (segment 0 is provably ignored by the reference)

// ws float layout:
//   [0, 128)      counts[b][s]
//   [128, 1152)   sums[b][s][c]
//   [1152, 1280)  pen_sum[b][s]

__global__ __launch_bounds__(256) void accum_kernel(
    const float* __restrict__ emb, const int* __restrict__ lab,
    const int* __restrict__ msk, float* __restrict__ ws)
{
    const int b = blockIdx.y;
    const int wave = threadIdx.x >> 6;
    __shared__ float lsum[4][SEGS][CCH];
    __shared__ float lcnt[4][SEGS];
    for (int i = threadIdx.x; i < 4 * SEGS * CCH; i += 256) (&lsum[0][0][0])[i] = 0.f;
    for (int i = threadIdx.x; i < 4 * SEGS; i += 256) (&lcnt[0][0])[i] = 0.f;
    __syncthreads();

    const float* eb = emb + (size_t)b * CCH * HW;
    const int4* lb = (const int4*)(lab + (size_t)b * HW);
    const int4* mb = (const int4*)(msk + (size_t)b * HW);

    const int ng = HW / 4;
    for (int g = blockIdx.x * 256 + threadIdx.x; g < ng; g += gridDim.x * 256) {
        int4 l4 = lb[g];
        int4 m4 = mb[g];
        int id[4];
        id[0] = m4.x ? l4.x : 0;
        id[1] = m4.y ? l4.y : 0;
        id[2] = m4.z ? l4.z : 0;
        id[3] = m4.w ? l4.w : 0;
#pragma unroll
        for (int j = 0; j < 4; ++j)
            if (id[j]) atomicAdd(&lcnt[wave][id[j] - 1], 1.0f);
#pragma unroll
        for (int c = 0; c < CCH; ++c) {
            float4 e4 = ((const float4*)(eb + (size_t)c * HW))[g];
            float ev[4] = {e4.x, e4.y, e4.z, e4.w};
#pragma unroll
            for (int j = 0; j < 4; ++j)
                if (id[j]) atomicAdd(&lsum[wave][id[j] - 1][c], ev[j]);
        }
    }
    __syncthreads();
    for (int i = threadIdx.x; i < SEGS * CCH; i += 256) {
        float v = (&lsum[0][0][0])[i] + (&lsum[1][0][0])[i]
                + (&lsum[2][0][0])[i] + (&lsum[3][0][0])[i];
        if (v != 0.f) atomicAdd(&ws[128 + b * SEGS * CCH + i], v);
    }
    for (int i = threadIdx.x; i < SEGS; i += 256) {
        float v = lcnt[0][i] + lcnt[1][i] + lcnt[2][i] + lcnt[3][i];
        if (v != 0.f) atomicAdd(&ws[b * SEGS + i], v);
    }
}

__global__ __launch_bounds__(256) void pull_kernel(
    const float* __restrict__ emb, const int* __restrict__ lab,
    const int* __restrict__ msk, float* __restrict__ ws)
{
    const int b = blockIdx.y;
    const int wave = threadIdx.x >> 6;
    __shared__ float mt[CCH][SEGS];   // transposed means: bank-conflict-free divergent reads
    __shared__ float lpen[4][SEGS];
    for (int i = threadIdx.x; i < 4 * SEGS; i += 256) (&lpen[0][0])[i] = 0.f;
    if (threadIdx.x < SEGS * CCH) {
        int s = threadIdx.x & (SEGS - 1);
        int c = threadIdx.x >> 4;
        float cnt = ws[b * SEGS + s];
        mt[c][s] = ws[128 + (b * SEGS + s) * CCH + c] / fmaxf(cnt, 1.0f);
    }
    __syncthreads();

    const float* eb = emb + (size_t)b * CCH * HW;
    const int4* lb = (const int4*)(lab + (size_t)b * HW);
    const int4* mb = (const int4*)(msk + (size_t)b * HW);

    const int ng = HW / 4;
    for (int g = blockIdx.x * 256 + threadIdx.x; g < ng; g += gridDim.x * 256) {
        int4 l4 = lb[g];
        int4 m4 = mb[g];
        int id[4];
        id[0] = m4.x ? l4.x : 0;
        id[1] = m4.y ? l4.y : 0;
        id[2] = m4.z ? l4.z : 0;
        id[3] = m4.w ? l4.w : 0;
        int ix[4];
#pragma unroll
        for (int j = 0; j < 4; ++j) ix[j] = id[j] ? id[j] - 1 : 0;
        float ss[4] = {0.f, 0.f, 0.f, 0.f};
#pragma unroll
        for (int c = 0; c < CCH; ++c) {
            float4 e4 = ((const float4*)(eb + (size_t)c * HW))[g];
            float ev[4] = {e4.x, e4.y, e4.z, e4.w};
#pragma unroll
            for (int j = 0; j < 4; ++j) {
                float d = ev[j] - mt[c][ix[j]];
                ss[j] += d * d;
            }
        }
#pragma unroll
        for (int j = 0; j < 4; ++j) {
            if (id[j]) {
                float d = sqrtf(fmaxf(ss[j], 1e-12f));
                float h = fmaxf(d - 0.5f, 0.f);
                atomicAdd(&lpen[wave][ix[j]], h * h);
            }
        }
    }
    __syncthreads();
    for (int i = threadIdx.x; i < SEGS; i += 256) {
        float v = lpen[0][i] + lpen[1][i] + lpen[2][i] + lpen[3][i];
        if (v != 0.f) atomicAdd(&ws[1152 + b * SEGS + i], v);
    }
}

__global__ __launch_bounds__(256) void finalize_kernel(
    const float* __restrict__ ws, float* __restrict__ out)
{
    __shared__ float cnt[BATCH][SEGS];
    __shared__ float mu[BATCH][SEGS][CCH];
    __shared__ float pen[BATCH][SEGS];
    __shared__ float res[BATCH][3];

    for (int i = threadIdx.x; i < BATCH * SEGS; i += 256) {
        (&cnt[0][0])[i] = ws[i];
        (&pen[0][0])[i] = ws[1152 + i];
    }
    for (int i = threadIdx.x; i < BATCH * SEGS * CCH; i += 256) {
        float c = ws[i / CCH];                 // count straight from global
        (&mu[0][0][0])[i] = ws[128 + i] / fmaxf(c, 1.0f);
    }
    __syncthreads();

    const int b = threadIdx.x >> 5;   // 8 batches x 32-lane groups
    const int l = threadIdx.x & 31;

    // pull: lanes 0..15 handle segments
    float pullv = 0.f, Kf = 0.f;
    if (l < SEGS && cnt[b][l] > 0.f) {
        Kf = 1.f;
        pullv = pen[b][l] / cnt[b][l];       // pen_mean (count>0 => max(count,1)=count)
    }
    // push: 256 (i,j) slots over 32 lanes
    float hs = 0.f, np = 0.f;
    for (int p = l; p < 256; p += 32) {
        int i = p >> 4, j = p & 15;
        if (i < j && cnt[b][i] > 0.f && cnt[b][j] > 0.f) {
            float ssq = 0.f;
#pragma unroll
            for (int c = 0; c < CCH; ++c) {
                float d = mu[b][i][c] - mu[b][j][c];
                ssq += d * d;
            }
            float dist = sqrtf(fmaxf(ssq, 1e-12f));
            float h = fmaxf(3.0f - dist, 0.f);   // 2*DELTA_D = 3.0
            hs += h * h;
            np += 1.f;
        }
    }
#pragma unroll
    for (int m = 16; m >= 1; m >>= 1) {
        pullv += __shfl_xor(pullv, m);
        Kf    += __shfl_xor(Kf, m);
        hs    += __shfl_xor(hs, m);
        np    += __shfl_xor(np, m);
    }
    if (l == 0) {
        res[b][0] = (Kf > 0.f) ? pullv / Kf : 0.f;
        res[b][1] = (np > 0.f) ? hs / np : 0.f;
        res[b][2] = (Kf > 0.f) ? 1.f : 0.f;
    }
    __syncthreads();
    if (threadIdx.x == 0) {
        float sp = 0.f, sh = 0.f, nv = 0.f;
        for (int bb = 0; bb < BATCH; ++bb) {
            sp += res[bb][0] * res[bb][2];
            sh += res[bb][1] * res[bb][2];
            nv += res[bb][2];
        }
        nv = fmaxf(nv, 1.f);
        out[0] = sp / nv;
        out[1] = sh / nv;
    }
}

extern "C" void kernel_launch(void* const* d_in, const int* in_sizes, int n_in,
                              void* d_out, int out_size, void* d_ws, size_t ws_size,
                              hipStream_t stream)
{
    const float* emb = (const float*)d_in[0];
    const int* lab = (const int*)d_in[1];
    const int* msk = (const int*)d_in[2];
    float* out = (float*)d_out;
    float* ws = (float*)d_ws;

    hipMemsetAsync(d_ws, 0, 1280 * sizeof(float), stream);
    dim3 grid(128, BATCH);
    accum_kernel<<<grid, 256, 0, stream>>>(emb, lab, msk, ws);
    pull_kernel<<<grid, 256, 0, stream>>>(emb, lab, msk, ws);
    finalize_kernel<<<1, 256, 0, stream>>>(ws, out);
}